// Round 1
// baseline (106.640 us; speedup 1.0000x reference)
//
#include <hip/hip_runtime.h>
#include <hip/hip_bf16.h>
#include <math.h>

#define N 4096

__inline__ __device__ float waveReduceSum(float v) {
    #pragma unroll
    for (int o = 32; o > 0; o >>= 1) v += __shfl_down(v, o);
    return v;
}

// wx[j] = relu(dot(x, w_in[j, :])) — one block per row, float4 coalesced along k
__global__ __launch_bounds__(256) void k_wx(const float* __restrict__ x,
                                            const float* __restrict__ w_in,
                                            float* __restrict__ wx_out) {
    int j = blockIdx.x;
    const float4* row = reinterpret_cast<const float4*>(w_in + (size_t)j * N);
    const float4* xv  = reinterpret_cast<const float4*>(x);
    float sum = 0.f;
    #pragma unroll 4
    for (int k = threadIdx.x; k < N / 4; k += 256) {
        float4 a = row[k], c = xv[k];
        sum += a.x * c.x + a.y * c.y + a.z * c.z + a.w * c.w;
    }
    sum = waveReduceSum(sum);
    __shared__ float wsum[4];
    int wid = threadIdx.x >> 6, lane = threadIdx.x & 63;
    if (lane == 0) wsum[wid] = sum;
    __syncthreads();
    if (threadIdx.x == 0) {
        float t = wsum[0] + wsum[1] + wsum[2] + wsum[3];
        wx_out[j] = fmaxf(t, 0.f);
    }
}

// partial wh: part[c*N + j] = sum_{i in chunk c} hid[i] * (w[i,j] + alpha[i,j]*hebb[i,j])
__global__ __launch_bounds__(256) void k_wh_part(const float* __restrict__ hid,
                                                 const float* __restrict__ w,
                                                 const float* __restrict__ alpha,
                                                 const float* __restrict__ hebb,
                                                 float* __restrict__ part) {
    int j  = blockIdx.x * 256 + threadIdx.x;
    int i0 = blockIdx.y * 64;
    float sum = 0.f;
    #pragma unroll 4
    for (int i = i0; i < i0 + 64; ++i) {
        size_t off = (size_t)i * N + j;
        sum = fmaf(hid[i], fmaf(alpha[off], hebb[off], w[off]), sum);
    }
    part[(size_t)blockIdx.y * N + j] = sum;
}

// finalize wh, s = wx + wh, LayerNorm (two-pass), relu -> wy
__global__ __launch_bounds__(1024) void k_ln(const float* __restrict__ part,
                                             const float* __restrict__ b,
                                             const float* __restrict__ wx,
                                             const float* __restrict__ gamma,
                                             const float* __restrict__ beta,
                                             float* __restrict__ wh_out,
                                             float* __restrict__ wy_out) {
    __shared__ float red[16];
    __shared__ float bc[2];
    int tid = threadIdx.x;
    int wid = tid >> 6, lane = tid & 63;
    float sv[4];
    float lsum = 0.f;
    #pragma unroll
    for (int q = 0; q < 4; ++q) {
        int j = q * 1024 + tid;
        float acc = b[j];
        for (int c = 0; c < 64; ++c) acc += part[(size_t)c * N + j];
        wh_out[j] = acc;
        float s = acc + wx[j];
        sv[q] = s;
        lsum += s;
    }
    float wv = waveReduceSum(lsum);
    if (lane == 0) red[wid] = wv;
    __syncthreads();
    if (tid < 64) {
        float t = (tid < 16) ? red[tid] : 0.f;
        t = waveReduceSum(t);
        if (tid == 0) bc[0] = t * (1.f / N);
    }
    __syncthreads();
    float mean = bc[0];
    __syncthreads();
    float lsq = 0.f;
    #pragma unroll
    for (int q = 0; q < 4; ++q) { float d = sv[q] - mean; lsq += d * d; }
    wv = waveReduceSum(lsq);
    if (lane == 0) red[wid] = wv;
    __syncthreads();
    if (tid < 64) {
        float t = (tid < 16) ? red[tid] : 0.f;
        t = waveReduceSum(t);
        if (tid == 0) bc[1] = t * (1.f / N);
    }
    __syncthreads();
    float rstd = rsqrtf(bc[1] + 1e-5f);
    #pragma unroll
    for (int q = 0; q < 4; ++q) {
        int j = q * 1024 + tid;
        float ln = fmaf(gamma[j] * (sv[q] - mean), rstd, beta[j]);
        wy_out[j] = fmaxf(ln, 0.f);
    }
}

// partial eta: part[c*N + j] = sum_{i in chunk c} wh[i] * pred_eta[i,j]
__global__ __launch_bounds__(256) void k_eta_part(const float* __restrict__ wh,
                                                  const float* __restrict__ pe,
                                                  float* __restrict__ part) {
    int j  = blockIdx.x * 256 + threadIdx.x;
    int i0 = blockIdx.y * 64;
    float sum = 0.f;
    #pragma unroll 4
    for (int i = i0; i < i0 + 64; ++i) {
        sum = fmaf(wh[i], pe[(size_t)i * N + j], sum);
    }
    part[(size_t)blockIdx.y * N + j] = sum;
}

__global__ __launch_bounds__(256) void k_eta_fin(const float* __restrict__ part,
                                                 const float* __restrict__ pb,
                                                 float* __restrict__ eta) {
    int j = blockIdx.x * 256 + threadIdx.x;
    float s = pb[j];
    for (int c = 0; c < 64; ++c) s += part[(size_t)c * N + j];
    eta[j] = 1.f / (1.f + expf(-s));
}

// hebb_new[i,j] = (1-lamda)*hebb[i,j] + eta[i]*hid[i]*wh[j]
__global__ __launch_bounds__(256) void k_hebb(const float* __restrict__ hebb,
                                              const float* __restrict__ eta,
                                              const float* __restrict__ hid,
                                              const float* __restrict__ wh,
                                              const float* __restrict__ lamda,
                                              float* __restrict__ out) {
    int i  = blockIdx.y;
    int j0 = blockIdx.x * 1024 + threadIdx.x * 4;
    float decay = 1.f - lamda[0];
    float coef  = eta[i] * hid[i];
    const float4 h  = *reinterpret_cast<const float4*>(hebb + (size_t)i * N + j0);
    const float4 w4 = *reinterpret_cast<const float4*>(wh + j0);
    float4 r;
    r.x = fmaf(decay, h.x, coef * w4.x);
    r.y = fmaf(decay, h.y, coef * w4.y);
    r.z = fmaf(decay, h.z, coef * w4.z);
    r.w = fmaf(decay, h.w, coef * w4.w);
    *reinterpret_cast<float4*>(out + (size_t)i * N + j0) = r;
}

extern "C" void kernel_launch(void* const* d_in, const int* in_sizes, int n_in,
                              void* d_out, int out_size, void* d_ws, size_t ws_size,
                              hipStream_t stream) {
    const float* x         = (const float*)d_in[0];
    const float* hid       = (const float*)d_in[1];
    const float* hebb      = (const float*)d_in[2];
    const float* w_in      = (const float*)d_in[3];
    const float* w         = (const float*)d_in[4];
    const float* alpha     = (const float*)d_in[5];
    const float* b         = (const float*)d_in[6];
    const float* lamda     = (const float*)d_in[7];
    const float* pred_eta  = (const float*)d_in[8];
    const float* pred_eta_b= (const float*)d_in[9];
    const float* ln_gamma  = (const float*)d_in[10];
    const float* ln_beta   = (const float*)d_in[11];

    float* wy       = (float*)d_out;           // [4096]
    float* hebb_out = (float*)d_out + N;       // [4096*4096]

    float* ws   = (float*)d_ws;
    float* part = ws;                          // 64*4096 floats (reused for eta partials)
    float* wx   = ws + 64 * N;                 // 4096
    float* wh   = ws + 64 * N + N;             // 4096
    float* eta  = ws + 64 * N + 2 * N;         // 4096

    k_wx      <<<N, 256, 0, stream>>>(x, w_in, wx);
    k_wh_part <<<dim3(16, 64), 256, 0, stream>>>(hid, w, alpha, hebb, part);
    k_ln      <<<1, 1024, 0, stream>>>(part, b, wx, ln_gamma, ln_beta, wh, wy);
    k_eta_part<<<dim3(16, 64), 256, 0, stream>>>(wh, pred_eta, part);
    k_eta_fin <<<16, 256, 0, stream>>>(part, pred_eta_b, eta);
    k_hebb    <<<dim3(4, N), 256, 0, stream>>>(hebb, eta, hid, wh, lamda, hebb_out);
}

// Round 2
// 103.820 us; speedup vs baseline: 1.0272x; 1.0272x over previous
//
#include <hip/hip_runtime.h>
#include <hip/hip_bf16.h>
#include <math.h>

#define N 4096
#define CHUNK 32
#define NCHUNK (N / CHUNK)   // 128 row-chunks for column-GEMV partials

__inline__ __device__ float waveReduceSum(float v) {
    #pragma unroll
    for (int o = 32; o > 0; o >>= 1) v += __shfl_down(v, o);
    return v;
}

// wx[j] = relu(dot(x, w_in[j, :])) — one block per row, float4 coalesced along k
__global__ __launch_bounds__(256) void k_wx(const float* __restrict__ x,
                                            const float* __restrict__ w_in,
                                            float* __restrict__ wx_out) {
    int j = blockIdx.x;
    const float4* row = reinterpret_cast<const float4*>(w_in + (size_t)j * N);
    const float4* xv  = reinterpret_cast<const float4*>(x);
    float sum = 0.f;
    #pragma unroll
    for (int k = threadIdx.x; k < N / 4; k += 256) {
        float4 a = row[k], c = xv[k];
        sum += a.x * c.x + a.y * c.y + a.z * c.z + a.w * c.w;
    }
    sum = waveReduceSum(sum);
    __shared__ float wsum[4];
    int wid = threadIdx.x >> 6, lane = threadIdx.x & 63;
    if (lane == 0) wsum[wid] = sum;
    __syncthreads();
    if (threadIdx.x == 0) {
        float t = wsum[0] + wsum[1] + wsum[2] + wsum[3];
        wx_out[j] = fmaxf(t, 0.f);
    }
}

// partial wh over a 32-row chunk, float4 per lane:
// part[c*N + j] = sum_{i in chunk c} hid[i] * (w[i,j] + alpha[i,j]*hebb[i,j])
__global__ __launch_bounds__(256) void k_wh_part(const float* __restrict__ hid,
                                                 const float* __restrict__ w,
                                                 const float* __restrict__ alpha,
                                                 const float* __restrict__ hebb,
                                                 float* __restrict__ part) {
    int j0 = blockIdx.x * 1024 + threadIdx.x * 4;  // 4 x-blocks cover 4096 cols
    int i0 = blockIdx.y * CHUNK;
    const float4* w4 = reinterpret_cast<const float4*>(w);
    const float4* a4 = reinterpret_cast<const float4*>(alpha);
    const float4* h4 = reinterpret_cast<const float4*>(hebb);
    float4 acc = make_float4(0.f, 0.f, 0.f, 0.f);
    #pragma unroll 4
    for (int i = i0; i < i0 + CHUNK; ++i) {
        size_t idx = ((size_t)i * N + j0) >> 2;
        float4 wv = w4[idx];
        float4 av = a4[idx];
        float4 hv = h4[idx];
        float  h  = hid[i];
        acc.x = fmaf(h, fmaf(av.x, hv.x, wv.x), acc.x);
        acc.y = fmaf(h, fmaf(av.y, hv.y, wv.y), acc.y);
        acc.z = fmaf(h, fmaf(av.z, hv.z, wv.z), acc.z);
        acc.w = fmaf(h, fmaf(av.w, hv.w, wv.w), acc.w);
    }
    *reinterpret_cast<float4*>(part + (size_t)blockIdx.y * N + j0) = acc;
}

// wh[j] = b[j] + sum_c part[c*N + j]
__global__ __launch_bounds__(256) void k_wh_fin(const float* __restrict__ part,
                                                const float* __restrict__ b,
                                                float* __restrict__ wh) {
    int j = blockIdx.x * 256 + threadIdx.x;
    float s = b[j];
    #pragma unroll 8
    for (int c = 0; c < NCHUNK; ++c) s += part[(size_t)c * N + j];
    wh[j] = s;
}

// s = wx + wh, LayerNorm (two-pass), relu -> wy.  Only 16KB vectors touched.
__global__ __launch_bounds__(1024) void k_ln(const float* __restrict__ wh,
                                             const float* __restrict__ wx,
                                             const float* __restrict__ gamma,
                                             const float* __restrict__ beta,
                                             float* __restrict__ wy_out) {
    __shared__ float red[16];
    __shared__ float bc[2];
    int tid = threadIdx.x;
    int wid = tid >> 6, lane = tid & 63;
    float sv[4];
    float lsum = 0.f;
    #pragma unroll
    for (int q = 0; q < 4; ++q) {
        int j = q * 1024 + tid;
        float s = wh[j] + wx[j];
        sv[q] = s;
        lsum += s;
    }
    float wv = waveReduceSum(lsum);
    if (lane == 0) red[wid] = wv;
    __syncthreads();
    if (tid < 64) {
        float t = (tid < 16) ? red[tid] : 0.f;
        t = waveReduceSum(t);
        if (tid == 0) bc[0] = t * (1.f / N);
    }
    __syncthreads();
    float mean = bc[0];
    __syncthreads();
    float lsq = 0.f;
    #pragma unroll
    for (int q = 0; q < 4; ++q) { float d = sv[q] - mean; lsq += d * d; }
    wv = waveReduceSum(lsq);
    if (lane == 0) red[wid] = wv;
    __syncthreads();
    if (tid < 64) {
        float t = (tid < 16) ? red[tid] : 0.f;
        t = waveReduceSum(t);
        if (tid == 0) bc[1] = t * (1.f / N);
    }
    __syncthreads();
    float rstd = rsqrtf(bc[1] + 1e-5f);
    #pragma unroll
    for (int q = 0; q < 4; ++q) {
        int j = q * 1024 + tid;
        float ln = fmaf(gamma[j] * (sv[q] - mean), rstd, beta[j]);
        wy_out[j] = fmaxf(ln, 0.f);
    }
}

// partial eta over 32-row chunk: part[c*N + j] = sum_{i in chunk} wh[i]*pe[i,j]
__global__ __launch_bounds__(256) void k_eta_part(const float* __restrict__ wh,
                                                  const float* __restrict__ pe,
                                                  float* __restrict__ part) {
    int j0 = blockIdx.x * 1024 + threadIdx.x * 4;
    int i0 = blockIdx.y * CHUNK;
    const float4* p4 = reinterpret_cast<const float4*>(pe);
    float4 acc = make_float4(0.f, 0.f, 0.f, 0.f);
    #pragma unroll 4
    for (int i = i0; i < i0 + CHUNK; ++i) {
        size_t idx = ((size_t)i * N + j0) >> 2;
        float4 pv = p4[idx];
        float  h  = wh[i];
        acc.x = fmaf(h, pv.x, acc.x);
        acc.y = fmaf(h, pv.y, acc.y);
        acc.z = fmaf(h, pv.z, acc.z);
        acc.w = fmaf(h, pv.w, acc.w);
    }
    *reinterpret_cast<float4*>(part + (size_t)blockIdx.y * N + j0) = acc;
}

__global__ __launch_bounds__(256) void k_eta_fin(const float* __restrict__ part,
                                                 const float* __restrict__ pb,
                                                 float* __restrict__ eta) {
    int j = blockIdx.x * 256 + threadIdx.x;
    float s = pb[j];
    #pragma unroll 8
    for (int c = 0; c < NCHUNK; ++c) s += part[(size_t)c * N + j];
    eta[j] = 1.f / (1.f + expf(-s));
}

// hebb_new[i,j] = (1-lamda)*hebb[i,j] + eta[i]*hid[i]*wh[j]
__global__ __launch_bounds__(256) void k_hebb(const float* __restrict__ hebb,
                                              const float* __restrict__ eta,
                                              const float* __restrict__ hid,
                                              const float* __restrict__ wh,
                                              const float* __restrict__ lamda,
                                              float* __restrict__ out) {
    int i  = blockIdx.y;
    int j0 = blockIdx.x * 1024 + threadIdx.x * 4;
    float decay = 1.f - lamda[0];
    float coef  = eta[i] * hid[i];
    const float4 h  = *reinterpret_cast<const float4*>(hebb + (size_t)i * N + j0);
    const float4 w4 = *reinterpret_cast<const float4*>(wh + j0);
    float4 r;
    r.x = fmaf(decay, h.x, coef * w4.x);
    r.y = fmaf(decay, h.y, coef * w4.y);
    r.z = fmaf(decay, h.z, coef * w4.z);
    r.w = fmaf(decay, h.w, coef * w4.w);
    *reinterpret_cast<float4*>(out + (size_t)i * N + j0) = r;
}

extern "C" void kernel_launch(void* const* d_in, const int* in_sizes, int n_in,
                              void* d_out, int out_size, void* d_ws, size_t ws_size,
                              hipStream_t stream) {
    const float* x         = (const float*)d_in[0];
    const float* hid       = (const float*)d_in[1];
    const float* hebb      = (const float*)d_in[2];
    const float* w_in      = (const float*)d_in[3];
    const float* w         = (const float*)d_in[4];
    const float* alpha     = (const float*)d_in[5];
    const float* b         = (const float*)d_in[6];
    const float* lamda     = (const float*)d_in[7];
    const float* pred_eta  = (const float*)d_in[8];
    const float* pred_eta_b= (const float*)d_in[9];
    const float* ln_gamma  = (const float*)d_in[10];
    const float* ln_beta   = (const float*)d_in[11];

    float* wy       = (float*)d_out;           // [4096]
    float* hebb_out = (float*)d_out + N;       // [4096*4096]

    float* ws   = (float*)d_ws;
    float* part = ws;                          // NCHUNK*4096 floats = 2MB (reused for eta)
    float* wx   = ws + NCHUNK * N;             // 4096
    float* wh   = ws + NCHUNK * N + N;         // 4096
    float* eta  = ws + NCHUNK * N + 2 * N;     // 4096

    k_wx      <<<N, 256, 0, stream>>>(x, w_in, wx);
    k_wh_part <<<dim3(4, NCHUNK), 256, 0, stream>>>(hid, w, alpha, hebb, part);
    k_wh_fin  <<<16, 256, 0, stream>>>(part, b, wh);
    k_ln      <<<1, 1024, 0, stream>>>(wh, wx, ln_gamma, ln_beta, wy);
    k_eta_part<<<dim3(4, NCHUNK), 256, 0, stream>>>(wh, pred_eta, part);
    k_eta_fin <<<16, 256, 0, stream>>>(part, pred_eta_b, eta);
    k_hebb    <<<dim3(4, N), 256, 0, stream>>>(hebb, eta, hid, wh, lamda, hebb_out);
}